// Round 14
// baseline (407.074 us; speedup 1.0000x reference)
//
#include <hip/hip_runtime.h>
#include <hip/hip_bf16.h>

// Problem constants (match reference)
constexpr int B = 8192;
constexpr int G = 1024;
constexpr int E = 256;
constexpr int K = 2048;
constexpr float P_NULL = 0.1f;
constexpr int N_STEP = 4;

typedef unsigned short u16;
typedef short bf16x8 __attribute__((ext_vector_type(8)));
typedef float f32x4 __attribute__((ext_vector_type(4)));

// raw-sync primitives (step kernel pipelining)
#define S_BARRIER __builtin_amdgcn_s_barrier()
#define SCHED0 __builtin_amdgcn_sched_barrier(0)
#define WAIT_VM0 asm volatile("s_waitcnt vmcnt(0)" ::: "memory")
#define WAIT_LGKM0 asm volatile("s_waitcnt lgkmcnt(0)" ::: "memory")

// ---------------------------------------------------------------------------
// bf16 <-> f32 (RNE)
// ---------------------------------------------------------------------------
__device__ inline u16 f2bf(float f) {
    union { float f; uint32_t u; } cv;
    cv.f = f;
    const uint32_t u = cv.u;
    return (u16)((u + 0x7fffu + ((u >> 16) & 1u)) >> 16);
}
__device__ inline float bf2f(u16 h) {
    union { uint32_t u; float f; } cv;
    cv.u = ((uint32_t)h) << 16;
    return cv.f;
}
__device__ inline uint4 pack8(const float* v) {
    uint4 u;
    u.x = (uint32_t)f2bf(v[0]) | ((uint32_t)f2bf(v[1]) << 16);
    u.y = (uint32_t)f2bf(v[2]) | ((uint32_t)f2bf(v[3]) << 16);
    u.z = (uint32_t)f2bf(v[4]) | ((uint32_t)f2bf(v[5]) << 16);
    u.w = (uint32_t)f2bf(v[6]) | ((uint32_t)f2bf(v[7]) << 16);
    return u;
}

// async global->LDS, 16B per lane (LDS dest is lane-linear; global src is
// per-lane and may be permuted -> XOR-swizzle is applied on the GLOBAL side)
typedef __attribute__((address_space(1))) const void* gaddr_t;
typedef __attribute__((address_space(3))) void* laddr_t;
__device__ inline void gload_lds16(const void* g, void* l) {
    __builtin_amdgcn_global_load_lds((gaddr_t)g, (laddr_t)l, 16, 0, 0);
}

// XCD-aware tile swizzle (requires gridDim.y % 8 == 0)
__device__ inline void swizzle_tiles(int& tr, int& tc) {
    const int cx = gridDim.x, cy = gridDim.y;
    const int id = blockIdx.y * cx + blockIdx.x;
    const int k = id & 7;
    const int q = id >> 3;
    tr = k * (cy >> 3) + q / cx;
    tc = q % cx;
}

// ---------------------------------------------------------------------------
// Reduction helpers
// ---------------------------------------------------------------------------
__device__ inline float wave_sum(float v) {
#pragma unroll
    for (int off = 32; off > 0; off >>= 1) v += __shfl_down(v, off, 64);
    return v;
}

// ---------------------------------------------------------------------------
// f32 -> bf16 flat convert, 8 elems/thread
// ---------------------------------------------------------------------------
__global__ __launch_bounds__(256) void f2bf_kernel(
    const float* __restrict__ in, u16* __restrict__ out, int n) {
    const int i = (blockIdx.x * 256 + threadIdx.x) * 8;
    if (i + 7 >= n) {
        for (int j = i; j < n; ++j) out[j] = f2bf(in[j]);
        return;
    }
    const float4 a = *(const float4*)(in + i);
    const float4 b = *(const float4*)(in + i + 4);
    float v[8] = {a.x, a.y, a.z, a.w, b.x, b.y, b.z, b.w};
    *(uint4*)(out + i) = pack8(v);
}

// ---------------------------------------------------------------------------
// Fused prep: f32 (R,C) -> bf16 (R,C) copy + bf16 (C,R) transpose +
// csq[c] += (1/R) sum_r v^2.  grid (C/32, R/32), block 256.
// ---------------------------------------------------------------------------
__global__ __launch_bounds__(256) void prep_kernel(
    const float* __restrict__ in, u16* __restrict__ outN,
    u16* __restrict__ outT, float* __restrict__ csq, int R, int C,
    float inv_R) {
    __shared__ float tile[32][33];
    __shared__ float sred[8][32];
    const int bx = blockIdx.x * 32, by = blockIdx.y * 32;
    const int x = threadIdx.x & 31, y0 = threadIdx.x >> 5;
    float s = 0.f;
#pragma unroll
    for (int yy = 0; yy < 32; yy += 8) {
        const float v = in[(size_t)(by + y0 + yy) * C + bx + x];
        tile[y0 + yy][x] = v;
        outN[(size_t)(by + y0 + yy) * C + bx + x] = f2bf(v);
        s = fmaf(v, v, s);
    }
    sred[y0][x] = s;
    __syncthreads();
#pragma unroll
    for (int yy = 0; yy < 32; yy += 8)
        outT[(size_t)(bx + y0 + yy) * R + by + x] = f2bf(tile[x][y0 + yy]);
    if (y0 == 0) {
        float t = 0.f;
#pragma unroll
        for (int k2 = 0; k2 < 8; ++k2) t += sred[k2][x];
        atomicAdd(csq + bx + x, t * inv_R);
    }
}

// ---------------------------------------------------------------------------
// MFMA bf16 GEMM, 256x128 tile, 512 threads (R5-PROVEN, encode/decode):
// u = exp(alpha*acc - bias[col]) -> bf16 C; Saux[row] += row-sum.
// Measured 50.5us, VGPR 60 + 64 AGPR, zero spill.
// 8 waves (4 row-bands x 2 col-halves), 64x64 out/wave (acc[4][4]).
// ---------------------------------------------------------------------------
__global__ __launch_bounds__(512, 2) void mfma_big_kernel(
    const u16* __restrict__ A, const u16* __restrict__ Bm,
    u16* __restrict__ C, const float* __restrict__ bias,
    float* __restrict__ Saux, int M, int N, int Kd, float alpha) {
    __shared__ u16 smem[32768];  // loop: As 16384 u16 | Bs 8192 u16; epi: all
    u16* As = smem;
    u16* Bs = smem + 16384;
    const int tid = threadIdx.x;
    int btr, btc;
    swizzle_tiles(btr, btc);
    const int row0 = btr * 256, col0 = btc * 128;
    const int lane = tid & 63, wave = tid >> 6;
    const int wr = wave >> 1, wc = wave & 1;  // row-band (0..3), col-half
    const int tx = lane & 15, quad = lane >> 4;
    const int txl = tx & 7;

    f32x4 acc[4][4] = {};

    for (int k0 = 0; k0 < Kd; k0 += 64) {
#pragma unroll
        for (int l = 0; l < 4; ++l) {
            const int lin = l * 4096 + tid * 8;
            const int r = lin >> 6;
            const int c = (((lin >> 3) & 7) ^ (r & 7)) * 8;  // XOR-swizzled src
            gload_lds16(A + (size_t)(row0 + r) * Kd + k0 + c, &As[lin]);
        }
#pragma unroll
        for (int l = 0; l < 2; ++l) {
            const int lin = l * 4096 + tid * 8;
            const int r = lin >> 6;
            const int c = (((lin >> 3) & 7) ^ (r & 7)) * 8;
            gload_lds16(Bm + (size_t)(col0 + r) * Kd + k0 + c, &Bs[lin]);
        }
        __syncthreads();
#pragma unroll
        for (int ks = 0; ks < 2; ++ks) {
            bf16x8 af[4], bfr[4];
            const int gsw = ((ks * 4 + quad) ^ txl) * 8;
#pragma unroll
            for (int i = 0; i < 4; ++i)
                af[i] = *(const bf16x8*)&As[(wr * 64 + i * 16 + tx) * 64 + gsw];
#pragma unroll
            for (int j = 0; j < 4; ++j)
                bfr[j] = *(const bf16x8*)&Bs[(wc * 64 + j * 16 + tx) * 64 + gsw];
#pragma unroll
            for (int i = 0; i < 4; ++i)
#pragma unroll
                for (int j = 0; j < 4; ++j)
                    acc[i][j] = __builtin_amdgcn_mfma_f32_16x16x32_bf16(
                        af[i], bfr[j], acc[i][j], 0, 0, 0);
        }
        __syncthreads();
    }

    // ---- epilogue: per-wave 64x64 patch at wave*4096 in LDS ----
    const int wbase = wave * 4096;
#pragma unroll
    for (int i = 0; i < 4; ++i) {
        float srow[4] = {0.f, 0.f, 0.f, 0.f};
#pragma unroll
        for (int j = 0; j < 4; ++j) {
            const int pcol = j * 16 + tx;
            const float cb = bias[col0 + wc * 64 + pcol];
#pragma unroll
            for (int r = 0; r < 4; ++r) {
                const int prow = i * 16 + quad * 4 + r;  // in-wave row 0..63
                const int paddr = wbase + prow * 64 +
                    (((pcol >> 3) ^ (prow & 7)) << 3) + (pcol & 7);
                const float v = __expf(fmaf(acc[i][j][r], alpha, -cb));
                srow[r] += v;
                smem[paddr] = f2bf(v);
            }
        }
#pragma unroll
        for (int r = 0; r < 4; ++r) {
            float s = srow[r];
            s += __shfl_xor(s, 1, 64);
            s += __shfl_xor(s, 2, 64);
            s += __shfl_xor(s, 4, 64);
            s += __shfl_xor(s, 8, 64);
            if (tx == 0)
                atomicAdd(&Saux[row0 + wr * 64 + i * 16 + quad * 4 + r], s);
        }
    }
    __syncthreads();

    // ---- write-out: row rr=tid>>1 (0..255), half hs (64 cols), coalesced ----
    const int rr = tid >> 1, hs = tid & 1;
#pragma unroll
    for (int u = 0; u < 8; ++u) {
        const int c = hs * 64 + u * 8;
        const int wv = (rr >> 6) * 2 + (c >> 6);  // source wave patch
        const int rl = rr & 63, cl = c & 63;
        const int pg = ((cl >> 3) ^ (rl & 7)) << 3;
        *(uint4*)(C + (size_t)(row0 + rr) * N + col0 + c) =
            *(const uint4*)&smem[wv * 4096 + rl * 64 + pg];
    }
}

// ---------------------------------------------------------------------------
// MFMA bf16 GEMM, 64x64 tile, for z0 = (e @ xb^T) / S_enc[row].
// ---------------------------------------------------------------------------
__global__ __launch_bounds__(256) void mfma_z64_kernel(
    const u16* __restrict__ A, const u16* __restrict__ Bm,
    u16* __restrict__ C, const float* __restrict__ Srow,
    int M, int N, int Kd) {
    __shared__ u16 As[64 * 64];
    __shared__ u16 Bs[64 * 64];
    const int tid = threadIdx.x;
    int btr, btc;
    swizzle_tiles(btr, btc);
    const int row0 = btr * 64, col0 = btc * 64;
    const int lane = tid & 63, wave = tid >> 6;
    const int wr = (wave >> 1) * 32, wc = (wave & 1) * 32;
    const int tx = lane & 15, quad = lane >> 4;
    const int txl = tx & 7;

    f32x4 acc[2][2] = {};

    for (int k0 = 0; k0 < Kd; k0 += 64) {
#pragma unroll
        for (int l = 0; l < 2; ++l) {
            const int lin = l * 2048 + tid * 8;
            const int r = lin >> 6;
            const int c = (((lin >> 3) & 7) ^ (r & 7)) * 8;
            gload_lds16(A + (size_t)(row0 + r) * Kd + k0 + c, &As[lin]);
        }
#pragma unroll
        for (int l = 0; l < 2; ++l) {
            const int lin = l * 2048 + tid * 8;
            const int r = lin >> 6;
            const int c = (((lin >> 3) & 7) ^ (r & 7)) * 8;
            gload_lds16(Bm + (size_t)(col0 + r) * Kd + k0 + c, &Bs[lin]);
        }
        __syncthreads();
#pragma unroll
        for (int ks = 0; ks < 2; ++ks) {
            bf16x8 af[2], bfr[2];
            const int gsw = ((ks * 4 + quad) ^ txl) * 8;
#pragma unroll
            for (int i = 0; i < 2; ++i)
                af[i] = *(const bf16x8*)&As[(wr + i * 16 + tx) * 64 + gsw];
#pragma unroll
            for (int j = 0; j < 2; ++j)
                bfr[j] = *(const bf16x8*)&Bs[(wc + j * 16 + tx) * 64 + gsw];
#pragma unroll
            for (int i = 0; i < 2; ++i)
#pragma unroll
                for (int j = 0; j < 2; ++j)
                    acc[i][j] = __builtin_amdgcn_mfma_f32_16x16x32_bf16(
                        af[i], bfr[j], acc[i][j], 0, 0, 0);
        }
        __syncthreads();
    }

#pragma unroll
    for (int i = 0; i < 2; ++i)
#pragma unroll
        for (int r = 0; r < 4; ++r) {
            const int row = row0 + wr + i * 16 + quad * 4 + r;
            const float sc = Srow ? (1.0f / Srow[row]) : 1.0f;
#pragma unroll
            for (int j = 0; j < 2; ++j) {
                const int col = col0 + wc + j * 16 + tx;
                C[(size_t)row * N + col] = f2bf(acc[i][j][r] * sc);
            }
        }
}

// ---------------------------------------------------------------------------
// STEP R14: K-split partials, 64 rows/block x P=4, 512 blocks = 2/CU,
// NOW with double-buffered chunk staging + counted waits (R1-proven
// 2-barrier scheme ported onto the R12-proven 64-row kernel).
// R13 post-mortem: step ~44us vs ~35us ingest floor -> drain stalls; both
// co-resident blocks phase-lock into staging. Fix: keep stage loads in
// flight across barriers so the sibling block's compute overlaps them.
// Per chunk kc (bufs p=kc&1): issue ereg+4 gloads for kc+1 -> bufs[p^1]
// (ereg FIRST so the es-write waits vmcnt(4), not 0); t-part; epilogue;
// B1 lgkm-only; z-part; es[p^1] write; B2 lgkm+vm0+barrier.
// LDS 77.5KB (dbuf xbT/xb/es; ws+redS overlay) -> still 2 blocks/CU.
// ---------------------------------------------------------------------------
constexpr int XBT0 = 0;        // [32k][256e] granule-XOR8, 8192 u16
constexpr int XBT1 = 8192;
constexpr int XB0 = 16384;     // [256e][32k] granule-XOR4, 8192 u16
constexpr int XB1 = 24576;
constexpr int ES0 = 32768;     // [64r][36k-padded], 2304 u16
constexpr int ES1 = 35072;
constexpr int WSO = 37376;     // [64r][36k-padded], 2304 u16 (redS overlays)
constexpr int SMEM_U16 = 39680;

__global__ __launch_bounds__(512, 4) void step_part_kernel(
    const u16* __restrict__ Z,      // (B,E) current z
    const u16* __restrict__ XbT,    // (K,E)
    const u16* __restrict__ Xb,     // (E,K)
    const u16* __restrict__ Ebf,    // (B,K) unnormalized encode weights
    const float* __restrict__ c2b,  // (K)
    u16* __restrict__ Zp,           // (4,B,E) bf16 partials
    float* __restrict__ Sp) {       // (4,B) f32 partials
    __shared__ u16 smem[SMEM_U16];
    const int tid = threadIdx.x;
    const int lane = tid & 63, wave = tid >> 6;
    const int rf = wave >> 1, kf = wave & 1;  // row-frag(16), k/e-half
    const int tx = lane & 15, quad = lane >> 4;
    const int part = blockIdx.x & 3;
    const int row0 = (blockIdx.x >> 2) * 64;
    const int kbase = part * 512;
    const float ascale = 2.0f / (float)E;
    const int kcol = kf * 16 + tx;   // lane's k-col in chunk (0..31)
    const int erow_ = tid >> 3;      // e stage: row (0..63)
    const int eg_ = tid & 7;         // e stage: 4-col group
    const int ewaddr = erow_ * 36 + eg_ * 4;  // padded es/ws row stride 36

    // ---- prologue: z band [64][256] granule-XOR8 into smem[0..16384) ----
#pragma unroll
    for (int l = 0; l < 4; ++l) {
        const int lin = l * 4096 + tid * 8;
        const int r = lin >> 8, gf = (lin >> 3) & 31;
        const int eoff = ((gf & 24) | ((gf & 7) ^ (r & 7))) << 3;
        gload_lds16(Z + (size_t)(row0 + r) * E + eoff, &smem[lin]);
    }
    // e chunk 0 + cb chunk 0 to regs
    uint2 ereg = *(const uint2*)&Ebf[(size_t)(row0 + erow_) * K + kbase + eg_ * 4];
    float cb = c2b[kbase + kcol];
    WAIT_VM0;
    SCHED0;
    S_BARRIER;
    SCHED0;

    // z A-frags for this wave's 16 rows: af[s], s covers E=256
    bf16x8 af[8];
    {
        const int arow = rf * 16 + tx;
#pragma unroll
        for (int s = 0; s < 8; ++s) {
            const int g = s * 4 + quad;
            const int gp = (g & 24) | ((g & 7) ^ (arow & 7));
            af[s] = *(const bf16x8*)&smem[arow * 256 + gp * 8];
        }
    }
    // es[0] write (region disjoint from z band)
    *(uint2*)&smem[ES0 + ewaddr] = ereg;
    WAIT_LGKM0;  // af reads + es0 write done before staging overwrites z band
    SCHED0;
    S_BARRIER;
    SCHED0;

    // stage chunk 0 into buffers 0
#pragma unroll
    for (int l = 0; l < 2; ++l) {
        const int lin = l * 4096 + tid * 8;
        const int r = lin >> 8, gf = (lin >> 3) & 31;
        const int eoff = ((gf & 24) | ((gf & 7) ^ (r & 7))) << 3;
        gload_lds16(XbT + (size_t)(kbase + r) * E + eoff, &smem[XBT0 + lin]);
    }
#pragma unroll
    for (int l = 0; l < 2; ++l) {
        const int lin = l * 4096 + tid * 8;
        const int e = lin >> 5, gq = (lin >> 3) & 3;
        const int koff = (gq ^ (e & 3) ^ ((e >> 2) & 3)) << 3;
        gload_lds16(Xb + (size_t)e * K + kbase + koff, &smem[XB0 + lin]);
    }
    WAIT_VM0;
    SCHED0;
    S_BARRIER;
    SCHED0;

    f32x4 acc2[8] = {};   // z' partial acc: [e-frag f] for rows rf*16..
    float srow[4] = {};   // Sw partials (this wave's rows x its kcols)

    for (int kc = 0; kc < 16; ++kc) {
        const int p = kc & 1;
        const int xbtP = p ? XBT1 : XBT0;
        const int xbP = p ? XB1 : XB0;
        const int esP = p ? ES1 : ES0;
        float cbn = 0.f;
        // ---- 1. issue stage for kc+1 -> bufs[p^1]; ereg FIRST ----
        if (kc < 15) {
            const int kn0 = kbase + (kc + 1) * 32;
            ereg = *(const uint2*)&Ebf[(size_t)(row0 + erow_) * K + kn0 + eg_ * 4];
            cbn = c2b[kn0 + kcol];
            const int xbtN = p ? XBT0 : XBT1;
            const int xbN = p ? XB0 : XB1;
#pragma unroll
            for (int l = 0; l < 2; ++l) {
                const int lin = l * 4096 + tid * 8;
                const int r = lin >> 8, gf = (lin >> 3) & 31;
                const int eoff = ((gf & 24) | ((gf & 7) ^ (r & 7))) << 3;
                gload_lds16(XbT + (size_t)(kn0 + r) * E + eoff,
                            &smem[xbtN + lin]);
            }
#pragma unroll
            for (int l = 0; l < 2; ++l) {
                const int lin = l * 4096 + tid * 8;
                const int e = lin >> 5, gq = (lin >> 3) & 3;
                const int koff = (gq ^ (e & 3) ^ ((e >> 2) & 3)) << 3;
                gload_lds16(Xb + (size_t)e * K + kn0 + koff, &smem[xbN + lin]);
            }
        }
        SCHED0;  // pin stage issue above compute

        // ---- 2. t-part: ta = z(rows rf*16..) @ xbT(k-col = kcol) ----
        f32x4 ta = {};
#pragma unroll
        for (int s = 0; s < 8; ++s) {
            const int g = s * 4 + quad;
            const int gp = (g & 24) | ((g & 7) ^ (kcol & 7));
            const bf16x8 bfr = *(const bf16x8*)&smem[xbtP + kcol * 256 + gp * 8];
            ta = __builtin_amdgcn_mfma_f32_16x16x32_bf16(af[s], bfr, ta, 0, 0, 0);
        }

        // ---- 3. epilogue: w = e * exp(t*ascale - cb) -> ws; Sw partial ----
#pragma unroll
        for (int r = 0; r < 4; ++r) {
            const int prow = rf * 16 + quad * 4 + r;
            const int pa = prow * 36 + kcol;
            const float ev = bf2f(smem[esP + pa]);
            const float wv = ev * __expf(fmaf(ta[r], ascale, -cb));
            srow[r] += wv;
            smem[WSO + pa] = f2bf(wv);
        }
        // ---- B1: ws visible (lgkm only; stage loads stay in flight) ----
        WAIT_LGKM0;
        SCHED0;
        S_BARRIER;
        SCHED0;

        // ---- 4. z-part: acc2 += w(rows rf*16, 32k) @ xbT(32k, e=kf*128..) ----
        const bf16x8 a2 =
            *(const bf16x8*)&smem[WSO + (rf * 16 + tx) * 36 + quad * 8];
#pragma unroll
        for (int f = 0; f < 8; ++f) {
            const int ecol = kf * 128 + f * 16 + tx;
            const int gq = quad ^ (ecol & 3) ^ ((ecol >> 2) & 3);
            const bf16x8 b2 = *(const bf16x8*)&smem[xbP + ecol * 32 + gq * 8];
            acc2[f] = __builtin_amdgcn_mfma_f32_16x16x32_bf16(a2, b2, acc2[f],
                                                              0, 0, 0);
        }
        // ---- 5. es(kc+1) write (compiler waits vmcnt(4) for ereg only) ----
        if (kc < 15) {
            const int esN = p ? ES0 : ES1;
            *(uint2*)&smem[esN + ewaddr] = ereg;
        }
        cb = cbn;
        // ---- B2: stage kc+1 arrived; es write + all bufs[p]/ws reads done ----
        WAIT_LGKM0;
        SCHED0;
        WAIT_VM0;
        S_BARRIER;
        SCHED0;
    }

    // ---- Sw partials: reduce over tx, combine kf-halves via LDS overlay ----
    float* redS = (float*)&smem[WSO];  // ws dead after loop; 128 floats
#pragma unroll
    for (int r = 0; r < 4; ++r) {
        float s = srow[r];
        s += __shfl_xor(s, 1, 64);
        s += __shfl_xor(s, 2, 64);
        s += __shfl_xor(s, 4, 64);
        s += __shfl_xor(s, 8, 64);
        if (tx == 0) redS[kf * 64 + rf * 16 + quad * 4 + r] = s;
    }
    __syncthreads();
    if (tid < 64)
        Sp[(size_t)part * B + row0 + tid] = redS[tid] + redS[64 + tid];

    // ---- Zp stores: bf16 partials ----
#pragma unroll
    for (int f = 0; f < 8; ++f)
#pragma unroll
        for (int r = 0; r < 4; ++r) {
            const int row = rf * 16 + quad * 4 + r;
            const int e = kf * 128 + f * 16 + tx;
            Zp[((size_t)part * B + row0 + row) * E + e] = f2bf(acc2[f][r]);
        }
}

// ---------------------------------------------------------------------------
// norm: z[row][e] = (sum_p Zp[p][row][e]) / (sum_p Sp[p][row]) -> bf16.
// Zp is bf16. Optionally (final step) also emits x2[row] =
// mean(z_rounded^2), replacing the separate rowmeansq kernel.
// grid B*E/2048 = 1024, block 256, 8 elems/thread (32 threads per row).
// ---------------------------------------------------------------------------
__global__ __launch_bounds__(256) void norm_kernel(
    const u16* __restrict__ Zp, const float* __restrict__ Sp,
    u16* __restrict__ Z, float* __restrict__ x2out) {
    const int gidx = blockIdx.x * 256 + threadIdx.x;
    const int row = gidx >> 5;
    const int e0 = (gidx & 31) * 8;
    const float s = Sp[row] + Sp[B + row] + Sp[2 * B + row] + Sp[3 * B + row];
    const float inv = 1.0f / s;
    const size_t base = (size_t)row * E + e0;
    float v[8] = {0.f, 0.f, 0.f, 0.f, 0.f, 0.f, 0.f, 0.f};
#pragma unroll
    for (int p = 0; p < 4; ++p) {
        const uint4 b = *(const uint4*)(Zp + (size_t)p * B * E + base);
        const uint32_t w[4] = {b.x, b.y, b.z, b.w};
#pragma unroll
        for (int q = 0; q < 4; ++q) {
            v[q * 2] += bf2f((u16)(w[q] & 0xffffu));
            v[q * 2 + 1] += bf2f((u16)(w[q] >> 16));
        }
    }
#pragma unroll
    for (int j = 0; j < 8; ++j) v[j] *= inv;
    *(uint4*)(Z + base) = pack8(v);
    if (x2out) {
        float s2 = 0.f;
#pragma unroll
        for (int j = 0; j < 8; ++j) {
            const float zr = bf2f(f2bf(v[j]));  // match bf16-rounded z
            s2 = fmaf(zr, zr, s2);
        }
        s2 += __shfl_xor(s2, 1, 32);
        s2 += __shfl_xor(s2, 2, 32);
        s2 += __shfl_xor(s2, 4, 32);
        s2 += __shfl_xor(s2, 8, 32);
        s2 += __shfl_xor(s2, 16, 32);
        if ((gidx & 31) == 0) x2out[row] = s2 * (1.0f / (float)E);
    }
}

// ---------------------------------------------------------------------------
// MFMA bf16 GEMM (128x128 tile, 512 blocks = 2/CU) with fused MSE-loss
// epilogue: D = P_NULL*exp(x2[row]) + S0[row];
// loss[row] += (1/N)*sum_col (acc/D - X[row,col])^2   (X is bf16 img_bf)
// ---------------------------------------------------------------------------
__global__ __launch_bounds__(256) void mfma_loss_kernel(
    const u16* __restrict__ A, const u16* __restrict__ Bm,
    float* __restrict__ loss, const float* __restrict__ x2,
    const u16* __restrict__ X, const float* __restrict__ S0,
    int M, int N, int Kd) {
    __shared__ u16 As[128 * 64];
    __shared__ u16 Bs[128 * 64];
    const int tid = threadIdx.x;
    int btr, btc;
    swizzle_tiles(btr, btc);
    const int row0 = btr * 128, col0 = btc * 128;
    const int lane = tid & 63, wave = tid >> 6;
    const int wr = (wave >> 1) * 64, wc = (wave & 1) * 64;
    const int tx = lane & 15, quad = lane >> 4;
    const int txl = tx & 7;

    f32x4 acc[4][4] = {};

    for (int k0 = 0; k0 < Kd; k0 += 64) {
#pragma unroll
        for (int l = 0; l < 4; ++l) {
            const int lin = l * 2048 + tid * 8;
            const int r = lin >> 6;
            const int c = (((lin >> 3) & 7) ^ (r & 7)) * 8;
            gload_lds16(A + (size_t)(row0 + r) * Kd + k0 + c, &As[lin]);
        }
#pragma unroll
        for (int l = 0; l < 4; ++l) {
            const int lin = l * 2048 + tid * 8;
            const int r = lin >> 6;
            const int c = (((lin >> 3) & 7) ^ (r & 7)) * 8;
            gload_lds16(Bm + (size_t)(col0 + r) * Kd + k0 + c, &Bs[lin]);
        }
        __syncthreads();
#pragma unroll
        for (int ks = 0; ks < 2; ++ks) {
            bf16x8 af[4], bfr[4];
            const int gsw = ((ks * 4 + quad) ^ txl) * 8;
#pragma unroll
            for (int i = 0; i < 4; ++i)
                af[i] = *(const bf16x8*)&As[(wr + i * 16 + tx) * 64 + gsw];
#pragma unroll
            for (int j = 0; j < 4; ++j)
                bfr[j] = *(const bf16x8*)&Bs[(wc + j * 16 + tx) * 64 + gsw];
#pragma unroll
            for (int i = 0; i < 4; ++i)
#pragma unroll
                for (int j = 0; j < 4; ++j)
                    acc[i][j] = __builtin_amdgcn_mfma_f32_16x16x32_bf16(
                        af[i], bfr[j], acc[i][j], 0, 0, 0);
        }
        __syncthreads();
    }

    const float inv_n = 1.0f / (float)N;
#pragma unroll
    for (int i = 0; i < 4; ++i) {
#pragma unroll
        for (int r = 0; r < 4; ++r) {
            const int row = row0 + wr + i * 16 + quad * 4 + r;
            const float D = P_NULL * __expf(x2[row]) + S0[row];
            const float invD = 1.0f / D;
            float s = 0.f;
#pragma unroll
            for (int j = 0; j < 4; ++j) {
                const int col = col0 + wc + j * 16 + tx;
                const float d =
                    acc[i][j][r] * invD - bf2f(X[(size_t)row * N + col]);
                s = fmaf(d, d, s);
            }
            s += __shfl_xor(s, 1, 64);
            s += __shfl_xor(s, 2, 64);
            s += __shfl_xor(s, 4, 64);
            s += __shfl_xor(s, 8, 64);
            if (tx == 0) atomicAdd(&loss[row], s * inv_n);
        }
    }
}

// ---------------------------------------------------------------------------
extern "C" void kernel_launch(void* const* d_in, const int* in_sizes, int n_in,
                              void* d_out, int out_size, void* d_ws, size_t ws_size,
                              hipStream_t stream) {
    const float* images = (const float*)d_in[0];  // (B,G)
    const float* xa     = (const float*)d_in[1];  // (G,K)
    const float* xb     = (const float*)d_in[2];  // (E,K)
    float* out = (float*)d_out;                   // (B,)

    // workspace carve-up (u16 elements, all regions 16B-aligned)
    u16* img_bf = (u16*)d_ws;                      // B*G
    u16* xa_bf  = img_bf + (size_t)B * G;          // G*K
    u16* xaT_bf = xa_bf + (size_t)G * K;           // K*G
    u16* xb_bf  = xaT_bf + (size_t)K * G;          // E*K
    u16* xbT_bf = xb_bf + (size_t)E * K;           // K*E
    u16* e_bf   = xbT_bf + (size_t)K * E;          // B*K (unnormalized enc e)
    u16* wu_bf  = e_bf + (size_t)B * K;            // B*K (decode u)
    u16* z_bf   = wu_bf + (size_t)B * K;           // B*E
    float* c2a  = (float*)(z_bf + (size_t)B * E);  // K   --+ one memset
    float* c2b  = c2a + K;                         // K     |
    float* Svec = c2b + K;                         // 2*B --+ (S_enc, S0)
    float* x2z  = Svec + 2 * B;                    // B (fully written)
    float* Sp   = x2z + B;                         // 4*B (fully written/step)
    // Zp (4,B,E) bf16 = 16MB overlays wu_bf (B*K u16 = 32MB; wu only used
    // in decode, after the step loop).
    u16* Zp = wu_bf;

    (void)hipMemsetAsync(d_out, 0, (size_t)B * sizeof(float), stream);
    (void)hipMemsetAsync(c2a, 0, (size_t)(2 * K + 2 * B) * sizeof(float), stream);

    // prep: bf16 copies + transposes + column mean-squares (one read each)
    f2bf_kernel<<<(B * G) / 2048, 256, 0, stream>>>(images, img_bf, B * G);
    prep_kernel<<<dim3(K / 32, G / 32), 256, 0, stream>>>(
        xa, xa_bf, xaT_bf, c2a, G, K, 1.0f / (float)G);
    prep_kernel<<<dim3(K / 32, E / 32), 256, 0, stream>>>(
        xb, xb_bf, xbT_bf, c2b, E, K, 1.0f / (float)E);

    // encode (softmax eliminated): e = exp(images@xa*(2/G) - c2a), S_enc=rowsum
    float* S_enc = Svec;
    mfma_big_kernel<<<dim3(K / 128, B / 256), 512, 0, stream>>>(
        img_bf, xaT_bf, e_bf, c2a, S_enc, B, K, G, 2.0f / (float)G);

    // z0 = (e @ xb^T) / S_enc[row]   (== pik @ xb^T)
    mfma_z64_kernel<<<dim3(E / 64, B / 64), 256, 0, stream>>>(
        e_bf, xb_bf, z_bf, S_enc, B, E, K);

    // loop: K-split partial steps + normalize (w never hits HBM).
    // Final norm also emits x2 = mean(z^2), feeding decode directly.
    for (int s = 0; s < N_STEP; ++s) {
        step_part_kernel<<<512, 512, 0, stream>>>(
            z_bf, xbT_bf, xb_bf, e_bf, c2b, Zp, Sp);
        norm_kernel<<<(B * E) / 2048, 256, 0, stream>>>(
            Zp, Sp, z_bf, (s == N_STEP - 1) ? x2z : nullptr);
    }

    // decode: u = exp(z@xb*(2/E) - c2b) ; S0 = rowsum(u)
    float* S0 = Svec + B;
    mfma_big_kernel<<<dim3(K / 128, B / 256), 512, 0, stream>>>(
        z_bf, xbT_bf, wu_bf, c2b, S0, B, K, E, 2.0f / (float)E);

    // loss: recon = (u @ xa^T)/D[row], D = P_NULL*e^{x2}+S0 ;
    // loss[b] = mean_g (recon - images)^2  (X read as bf16 img_bf)
    mfma_loss_kernel<<<dim3(G / 128, B / 128), 256, 0, stream>>>(
        wu_bf, xa_bf, out, x2z, img_bf, S0, B, G, K);
}